// Round 1
// baseline (190.393 us; speedup 1.0000x reference)
//
#include <hip/hip_runtime.h>

#define N_USER 100000
#define N_ITEM 50000
#define N_NODES 150000
#define EMB 64
#define NNZ 4000000
#define BATCH 4096

// ws layout: [0,150000) byte flags; prop (150000x64 f32) at offset 150016 (16B aligned)
#define PROP_OFF 150016

// K1: one wave per output slot: mark flag, zero the prop row (idempotent across dups)
__global__ void mark_zero_kernel(const int* __restrict__ users,
                                 const int* __restrict__ pos_items,
                                 const int* __restrict__ neg_items,
                                 unsigned char* __restrict__ flags,
                                 float* __restrict__ prop) {
    int t = blockIdx.x * blockDim.x + threadIdx.x;
    int wave = t >> 6;          // 12288 waves
    int lane = t & 63;
    int k = wave >> 12;         // which of the 3 index arrays
    int i = wave & 4095;
    int node;
    if (k == 0)      node = users[i];
    else if (k == 1) node = N_USER + pos_items[i];
    else             node = N_USER + neg_items[i];
    prop[(size_t)node * EMB + lane] = 0.0f;
    if (lane == 0) flags[node] = 1;
}

// K2: one thread per edge; wave cooperates on the ~8% of edges whose row is needed
__global__ void spmm_kernel(const int* __restrict__ rows,
                            const int* __restrict__ cols,
                            const float* __restrict__ vals,
                            const float* __restrict__ user_emb,
                            const float* __restrict__ item_emb,
                            const unsigned char* __restrict__ flags,
                            float* __restrict__ prop) {
    int tid = blockIdx.x * blockDim.x + threadIdx.x;   // == edge index, grid covers NNZ exactly
    int lane = threadIdx.x & 63;
    int row = rows[tid];
    int col = cols[tid];
    float val = vals[tid];
    bool needed = flags[row] != 0;
    unsigned long long mask = __ballot(needed);
    while (mask) {
        int src = __ffsll((unsigned long long)mask) - 1;   // wave-uniform
        mask &= mask - 1;
        int r = __builtin_amdgcn_readlane(row, src);
        int c = __builtin_amdgcn_readlane(col, src);
        float v = __uint_as_float(__builtin_amdgcn_readlane(__float_as_uint(val), src));
        const float* x = (c < N_USER) ? (user_emb + (size_t)c * EMB)
                                      : (item_emb + (size_t)(c - N_USER) * EMB);
        atomicAdd(prop + (size_t)r * EMB + lane, v * x[lane]);
    }
}

// K3: out[k][i][lane] = (ego + 3*prop)/4 at the sampled nodes
__global__ void gather_kernel(const int* __restrict__ users,
                              const int* __restrict__ pos_items,
                              const int* __restrict__ neg_items,
                              const float* __restrict__ user_emb,
                              const float* __restrict__ item_emb,
                              const float* __restrict__ prop,
                              float* __restrict__ out) {
    int t = blockIdx.x * blockDim.x + threadIdx.x;
    int wave = t >> 6;
    int lane = t & 63;
    int k = wave >> 12;
    int i = wave & 4095;
    int node;
    if (k == 0)      node = users[i];
    else if (k == 1) node = N_USER + pos_items[i];
    else             node = N_USER + neg_items[i];
    float ego = (node < N_USER)
                    ? user_emb[(size_t)node * EMB + lane]
                    : item_emb[(size_t)(node - N_USER) * EMB + lane];
    float p = prop[(size_t)node * EMB + lane];
    out[t] = (ego + 3.0f * p) * 0.25f;
}

extern "C" void kernel_launch(void* const* d_in, const int* in_sizes, int n_in,
                              void* d_out, int out_size, void* d_ws, size_t ws_size,
                              hipStream_t stream) {
    const int*   adj_rows = (const int*)  d_in[0];
    const int*   adj_cols = (const int*)  d_in[1];
    const float* adj_vals = (const float*)d_in[2];
    const float* user_emb = (const float*)d_in[3];
    const float* item_emb = (const float*)d_in[4];
    const int*   users    = (const int*)  d_in[5];
    const int*   pos      = (const int*)  d_in[6];
    const int*   neg      = (const int*)  d_in[7];
    float* out = (float*)d_out;

    unsigned char* flags = (unsigned char*)d_ws;
    float* prop = (float*)((char*)d_ws + PROP_OFF);

    hipMemsetAsync(flags, 0, N_NODES, stream);

    // 3*BATCH*EMB = 786432 threads -> 3072 blocks of 256
    mark_zero_kernel<<<3072, 256, 0, stream>>>(users, pos, neg, flags, prop);

    // NNZ = 4,000,000 threads -> 15625 blocks of 256 (exact)
    spmm_kernel<<<15625, 256, 0, stream>>>(adj_rows, adj_cols, adj_vals,
                                           user_emb, item_emb, flags, prop);

    gather_kernel<<<3072, 256, 0, stream>>>(users, pos, neg,
                                            user_emb, item_emb, prop, out);
}